// Round 1
// baseline (598.610 us; speedup 1.0000x reference)
//
#include <hip/hip_runtime.h>

#define DMODEL 512
#define LSEQ   512
#define BATCH  4
#define NHEAD  8    // feature axis inside each "head"
#define DKH    64   // the module's heads axis

// ---------------- LayerNorm over q ----------------
__global__ __launch_bounds__(256) void ln_kernel(const float* __restrict__ q,
    const float* __restrict__ gamma, const float* __restrict__ beta,
    float* __restrict__ qn) {
  int row = blockIdx.x;                  // 0..B*L-1
  const float* x = q + (size_t)row * DMODEL;
  int t = threadIdx.x;                   // 256 threads, 2 elems each
  float v0 = x[t];
  float v1 = x[t + 256];
  float s  = v0 + v1;
  float ss = v0 * v0 + v1 * v1;
  #pragma unroll
  for (int o = 32; o >= 1; o >>= 1) {
    s  += __shfl_down(s, o);
    ss += __shfl_down(ss, o);
  }
  __shared__ float ls[4], lss[4];
  __shared__ float smu, srstd;
  int wid = t >> 6, lane = t & 63;
  if (lane == 0) { ls[wid] = s; lss[wid] = ss; }
  __syncthreads();
  if (t == 0) {
    float S  = ls[0] + ls[1] + ls[2] + ls[3];
    float SS = lss[0] + lss[1] + lss[2] + lss[3];
    float mu  = S * (1.0f / DMODEL);
    float var = SS * (1.0f / DMODEL) - mu * mu;
    smu = mu;
    srstd = rsqrtf(var + 1e-6f);
  }
  __syncthreads();
  float mu = smu, rstd = srstd;
  float* o = qn + (size_t)row * DMODEL;
  o[t]       = (v0 - mu) * rstd * gamma[t]       + beta[t];
  o[t + 256] = (v1 - mu) * rstd * gamma[t + 256] + beta[t + 256];
}

// ---------------- 64x64-tile fp32 GEMM body: C[r,o] = sum_d A[r,d] * W[o,d] ----------------
__device__ __forceinline__ void gemm64_body(const float* __restrict__ A,
    const float* __restrict__ W, float* __restrict__ C,
    const float* __restrict__ bias, const float* __restrict__ resid) {
  __shared__ float As[16][68];   // +4 pad: float4-aligned, conflict-free
  __shared__ float Ws[16][68];
  const int t = threadIdx.x;
  const int row0 = blockIdx.y * 64, col0 = blockIdx.x * 64;
  const int lr = t >> 2;           // 0..63 (tile row for staging)
  const int lk = (t & 3) << 2;     // 0,4,8,12 (k offset for staging)
  const int tx = t & 15, ty = t >> 4;
  float acc[4][4] = {};
  for (int k0 = 0; k0 < DMODEL; k0 += 16) {
    float4 a = *(const float4*)(A + (size_t)(row0 + lr) * DMODEL + k0 + lk);
    float4 w = *(const float4*)(W + (size_t)(col0 + lr) * DMODEL + k0 + lk);
    if (k0) __syncthreads();
    As[lk+0][lr] = a.x; As[lk+1][lr] = a.y; As[lk+2][lr] = a.z; As[lk+3][lr] = a.w;
    Ws[lk+0][lr] = w.x; Ws[lk+1][lr] = w.y; Ws[lk+2][lr] = w.z; Ws[lk+3][lr] = w.w;
    __syncthreads();
    #pragma unroll
    for (int kk = 0; kk < 16; kk++) {
      float4 av = *(const float4*)&As[kk][ty << 2];
      float4 wv = *(const float4*)&Ws[kk][tx << 2];
      float ar[4] = {av.x, av.y, av.z, av.w};
      float wr[4] = {wv.x, wv.y, wv.z, wv.w};
      #pragma unroll
      for (int i = 0; i < 4; i++)
        #pragma unroll
        for (int j = 0; j < 4; j++)
          acc[i][j] = fmaf(ar[i], wr[j], acc[i][j]);
    }
  }
  #pragma unroll
  for (int i = 0; i < 4; i++) {
    int r = row0 + (ty << 2) + i;
    int c = col0 + (tx << 2);
    float4 o = {acc[i][0], acc[i][1], acc[i][2], acc[i][3]};
    if (bias) {
      o.x += bias[c]; o.y += bias[c+1]; o.z += bias[c+2]; o.w += bias[c+3];
    }
    if (resid) {
      float4 rv = *(const float4*)(resid + (size_t)r * DMODEL + c);
      o.x += rv.x; o.y += rv.y; o.z += rv.z; o.w += rv.w;
    }
    *(float4*)(C + (size_t)r * DMODEL + c) = o;
  }
}

// z=0: Qp = qn@Wq^T; z=1: Kp = k@Wk^T; z=2: Vp = v@Wv^T
__global__ __launch_bounds__(256) void proj_kernel(
    const float* __restrict__ qn, const float* __restrict__ kin, const float* __restrict__ vin,
    const float* __restrict__ Wq, const float* __restrict__ Wk, const float* __restrict__ Wv,
    float* __restrict__ Qp, float* __restrict__ Kp, float* __restrict__ Vp) {
  const float* A; const float* W; float* C;
  if (blockIdx.z == 0)      { A = qn;  W = Wq; C = Qp; }
  else if (blockIdx.z == 1) { A = kin; W = Wk; C = Kp; }
  else                      { A = vin; W = Wv; C = Vp; }
  gemm64_body(A, W, C, nullptr, nullptr);
}

__global__ __launch_bounds__(256) void fc_kernel(
    const float* __restrict__ AO, const float* __restrict__ Wfc,
    const float* __restrict__ bfc, const float* __restrict__ resid,
    float* __restrict__ out) {
  gemm64_body(AO, Wfc, out, bfc, resid);
}

// ---------------- attention: per (b, dk) head slice ----------------
// grid: (qtile 0..3, dk 0..63, b 0..3); block 256 = 4 waves; wave handles 32 q rows
__global__ __launch_bounds__(256) void attn_kernel(
    const float* __restrict__ Qp, const float* __restrict__ Kp, const float* __restrict__ Vp,
    const float* __restrict__ sim, float* __restrict__ attn_out, float* __restrict__ AO) {
  __shared__ float Kt[NHEAD][LSEQ];   // transposed: consecutive lanes -> consecutive words
  __shared__ float Vt[NHEAD][LSEQ];
  __shared__ float Qt[128][NHEAD];
  const int qt = blockIdx.x, dk = blockIdx.y, b = blockIdx.z;
  const int t = threadIdx.x;
  const float* Kbase = Kp + ((size_t)b * LSEQ) * DMODEL + dk * NHEAD;
  const float* Vbase = Vp + ((size_t)b * LSEQ) * DMODEL + dk * NHEAD;
  for (int idx = t; idx < LSEQ * NHEAD; idx += 256) {
    int l = idx >> 3, j = idx & 7;
    Kt[j][l] = Kbase[(size_t)l * DMODEL + j];
    Vt[j][l] = Vbase[(size_t)l * DMODEL + j];
  }
  const float* Qbase = Qp + ((size_t)b * LSEQ + qt * 128) * DMODEL + dk * NHEAD;
  for (int idx = t; idx < 128 * NHEAD; idx += 256) {
    int l = idx >> 3, j = idx & 7;
    Qt[l][j] = Qbase[(size_t)l * DMODEL + j];
  }
  __syncthreads();

  const int wid = t >> 6, lane = t & 63;
  for (int qi = 0; qi < 32; qi++) {
    const int ql = wid * 32 + qi;        // 0..127
    const int q  = qt * 128 + ql;
    const size_t rowoff = (((size_t)(b * DKH + dk) * LSEQ) + q) * LSEQ;
    const float* simrow = sim + rowoff;
    float sv[8];
    #pragma unroll
    for (int c = 0; c < 8; c++) sv[c] = simrow[c * 64 + lane];
    float qreg[8];
    #pragma unroll
    for (int j = 0; j < 8; j++) qreg[j] = Qt[ql][j];
    float s[8];
    #pragma unroll
    for (int c = 0; c < 8; c++) {
      int kp = c * 64 + lane;
      float d = 0.0f;
      #pragma unroll
      for (int j = 0; j < 8; j++) d = fmaf(qreg[j], Kt[j][kp], d);
      s[c] = d * 0.125f + sv[c];   // / sqrt(DK=64) = /8
    }
    float m = s[0];
    #pragma unroll
    for (int c = 1; c < 8; c++) m = fmaxf(m, s[c]);
    #pragma unroll
    for (int o = 1; o < 64; o <<= 1) m = fmaxf(m, __shfl_xor(m, o));
    float e[8]; float sum = 0.0f;
    #pragma unroll
    for (int c = 0; c < 8; c++) { e[c] = __expf(s[c] - m); sum += e[c]; }
    #pragma unroll
    for (int o = 1; o < 64; o <<= 1) sum += __shfl_xor(sum, o);
    const float r = 1.0f / sum;
    float p[8];
    #pragma unroll
    for (int c = 0; c < 8; c++) p[c] = e[c] * r;
    float* arow = attn_out + rowoff;
    #pragma unroll
    for (int c = 0; c < 8; c++) arow[c * 64 + lane] = p[c];
    // PV: out[q][j] = sum_k p[k] * V[k][j]
    float pv[8];
    #pragma unroll
    for (int j = 0; j < 8; j++) {
      float acc = 0.0f;
      #pragma unroll
      for (int c = 0; c < 8; c++) acc = fmaf(p[c], Vt[j][c * 64 + lane], acc);
      pv[j] = acc;
    }
    #pragma unroll
    for (int j = 0; j < 8; j++) {
      #pragma unroll
      for (int o = 1; o < 64; o <<= 1) pv[j] += __shfl_xor(pv[j], o);
    }
    if (lane == 0) {
      float* ao = AO + ((size_t)b * LSEQ + q) * DMODEL + dk * NHEAD;
      float4 o0 = {pv[0], pv[1], pv[2], pv[3]};
      float4 o1 = {pv[4], pv[5], pv[6], pv[7]};
      *(float4*)ao = o0;
      *(float4*)(ao + 4) = o1;
    }
  }
}

extern "C" void kernel_launch(void* const* d_in, const int* in_sizes, int n_in,
                              void* d_out, int out_size, void* d_ws, size_t ws_size,
                              hipStream_t stream) {
  const float* q    = (const float*)d_in[0];
  const float* k    = (const float*)d_in[1];
  const float* v    = (const float*)d_in[2];
  const float* sim  = (const float*)d_in[3];
  const float* Wq   = (const float*)d_in[4];
  const float* Wk   = (const float*)d_in[5];
  const float* Wv   = (const float*)d_in[6];
  const float* Wfc  = (const float*)d_in[7];
  const float* bfc  = (const float*)d_in[8];
  const float* ln_g = (const float*)d_in[9];
  const float* ln_b = (const float*)d_in[10];

  float* out  = (float*)d_out;                         // [B, L, DM]
  float* attn = out + (size_t)BATCH * LSEQ * DMODEL;   // [B, DKH, L, L]

  const size_t NTOK = (size_t)BATCH * LSEQ;            // 2048
  float* qn = (float*)d_ws;                            // [NTOK, DM]
  float* Qp = qn + NTOK * DMODEL;
  float* Kp = Qp + NTOK * DMODEL;
  float* Vp = Kp + NTOK * DMODEL;
  float* AO = qn;  // qn is dead after proj_kernel; reuse for head outputs

  ln_kernel<<<dim3(NTOK), dim3(256), 0, stream>>>(q, ln_g, ln_b, qn);
  proj_kernel<<<dim3(8, 32, 3), dim3(256), 0, stream>>>(qn, k, v, Wq, Wk, Wv, Qp, Kp, Vp);
  attn_kernel<<<dim3(4, DKH, BATCH), dim3(256), 0, stream>>>(Qp, Kp, Vp, sim, attn, AO);
  fc_kernel<<<dim3(8, 32, 1), dim3(256), 0, stream>>>(AO, Wfc, bfc, q, out);
}

// Round 2
// 584.454 us; speedup vs baseline: 1.0242x; 1.0242x over previous
//
#include <hip/hip_runtime.h>

#define DMODEL 512
#define LSEQ   512
#define BATCH  4
#define NTOK   2048   // BATCH*LSEQ

typedef __attribute__((ext_vector_type(8))) short bf8;
typedef __attribute__((ext_vector_type(4))) float f4;
typedef __attribute__((ext_vector_type(4))) unsigned short us4;
typedef __attribute__((ext_vector_type(8))) unsigned short us8;

__device__ __forceinline__ unsigned short bf16_rne(float f) {
  unsigned int u = __float_as_uint(f);
  u += 0x7FFFu + ((u >> 16) & 1u);
  return (unsigned short)(u >> 16);
}
__device__ __forceinline__ void split2(float f, unsigned short& h, unsigned short& l) {
  unsigned short hh = bf16_rne(f);
  float fh = __uint_as_float(((unsigned int)hh) << 16);
  h = hh;
  l = bf16_rne(f - fh);
}

// ---------------- LayerNorm over q -> bf16 hi/lo ----------------
__global__ __launch_bounds__(256) void ln_kernel(const float* __restrict__ q,
    const float* __restrict__ gamma, const float* __restrict__ beta,
    unsigned short* __restrict__ qh, unsigned short* __restrict__ qlo) {
  int row = blockIdx.x;
  const float* x = q + (size_t)row * DMODEL;
  int t = threadIdx.x;
  float v0 = x[t];
  float v1 = x[t + 256];
  float s  = v0 + v1;
  float ss = v0 * v0 + v1 * v1;
  #pragma unroll
  for (int o = 32; o >= 1; o >>= 1) {
    s  += __shfl_down(s, o);
    ss += __shfl_down(ss, o);
  }
  __shared__ float ls[4], lss[4];
  __shared__ float smu, srstd;
  int wid = t >> 6, lane = t & 63;
  if (lane == 0) { ls[wid] = s; lss[wid] = ss; }
  __syncthreads();
  if (t == 0) {
    float S  = ls[0] + ls[1] + ls[2] + ls[3];
    float SS = lss[0] + lss[1] + lss[2] + lss[3];
    float mu  = S * (1.0f / DMODEL);
    float var = SS * (1.0f / DMODEL) - mu * mu;
    smu = mu;
    srstd = rsqrtf(var + 1e-6f);
  }
  __syncthreads();
  float mu = smu, rstd = srstd;
  float n0 = (v0 - mu) * rstd * gamma[t]       + beta[t];
  float n1 = (v1 - mu) * rstd * gamma[t + 256] + beta[t + 256];
  unsigned short h, l;
  size_t base = (size_t)row * DMODEL;
  split2(n0, h, l); qh[base + t] = h;       qlo[base + t] = l;
  split2(n1, h, l); qh[base + t + 256] = h; qlo[base + t + 256] = l;
}

// ---------------- fp32 -> bf16 hi/lo converter (k, v, 4 weight mats) ----------------
__global__ __launch_bounds__(256) void conv_kernel(
    const float* __restrict__ k, const float* __restrict__ v,
    const float* __restrict__ Wq, const float* __restrict__ Wk,
    const float* __restrict__ Wv, const float* __restrict__ Wf,
    unsigned short* __restrict__ kh, unsigned short* __restrict__ kl,
    unsigned short* __restrict__ vh, unsigned short* __restrict__ vl,
    unsigned short* __restrict__ Wqh, unsigned short* __restrict__ Wql,
    unsigned short* __restrict__ Wkh, unsigned short* __restrict__ Wkl,
    unsigned short* __restrict__ Wvh, unsigned short* __restrict__ Wvl,
    unsigned short* __restrict__ Wfh, unsigned short* __restrict__ Wfl) {
  const float* src; unsigned short* dh; unsigned short* dl; int n;
  switch (blockIdx.y) {
    case 0:  src = k;  dh = kh;  dl = kl;  n = NTOK * DMODEL; break;
    case 1:  src = v;  dh = vh;  dl = vl;  n = NTOK * DMODEL; break;
    case 2:  src = Wq; dh = Wqh; dl = Wql; n = DMODEL * DMODEL; break;
    case 3:  src = Wk; dh = Wkh; dl = Wkl; n = DMODEL * DMODEL; break;
    case 4:  src = Wv; dh = Wvh; dl = Wvl; n = DMODEL * DMODEL; break;
    default: src = Wf; dh = Wfh; dl = Wfl; n = DMODEL * DMODEL; break;
  }
  int idx = blockIdx.x * 1024 + threadIdx.x * 4;
  if (idx >= n) return;
  float4 f = *(const float4*)(src + idx);
  us4 oh, ol;
  unsigned short h, l;
  split2(f.x, h, l); oh[0] = h; ol[0] = l;
  split2(f.y, h, l); oh[1] = h; ol[1] = l;
  split2(f.z, h, l); oh[2] = h; ol[2] = l;
  split2(f.w, h, l); oh[3] = h; ol[3] = l;
  *(us4*)(dh + idx) = oh;
  *(us4*)(dl + idx) = ol;
}

// ---------------- bf16x3 MFMA GEMM: C[M=2048? per grid][N] = A[M,K] * W[N,K]^T ----------------
// block 256 = 4 waves (2x2), wave tile 32x32 via 2x2 of 16x16x32 MFMA. K=512.
__device__ __forceinline__ void mfma_gemm_body(
    const unsigned short* __restrict__ Ah, const unsigned short* __restrict__ Al,
    const unsigned short* __restrict__ Wh, const unsigned short* __restrict__ Wl,
    float* __restrict__ C, const float* __restrict__ bias, const float* __restrict__ resid) {
  const int t = threadIdx.x;
  const int w = t >> 6, lane = t & 63;
  const int wm = w >> 1, wn = w & 1;
  const int r0 = blockIdx.y * 64 + wm * 32;
  const int c0 = blockIdx.x * 64 + wn * 32;
  const int lr = lane & 15, quad = lane >> 4;
  f4 acc[2][2] = {};
  for (int k0 = 0; k0 < DMODEL; k0 += 32) {
    const int ko = k0 + quad * 8;
    bf8 ah[2], al[2], bh[2], bl[2];
    #pragma unroll
    for (int mi = 0; mi < 2; mi++) {
      const size_t off = (size_t)(r0 + mi * 16 + lr) * DMODEL + ko;
      ah[mi] = *(const bf8*)(Ah + off);
      al[mi] = *(const bf8*)(Al + off);
    }
    #pragma unroll
    for (int ni = 0; ni < 2; ni++) {
      const size_t off = (size_t)(c0 + ni * 16 + lr) * DMODEL + ko;
      bh[ni] = *(const bf8*)(Wh + off);
      bl[ni] = *(const bf8*)(Wl + off);
    }
    #pragma unroll
    for (int mi = 0; mi < 2; mi++)
      #pragma unroll
      for (int ni = 0; ni < 2; ni++) {
        acc[mi][ni] = __builtin_amdgcn_mfma_f32_16x16x32_bf16(al[mi], bh[ni], acc[mi][ni], 0, 0, 0);
        acc[mi][ni] = __builtin_amdgcn_mfma_f32_16x16x32_bf16(ah[mi], bl[ni], acc[mi][ni], 0, 0, 0);
        acc[mi][ni] = __builtin_amdgcn_mfma_f32_16x16x32_bf16(ah[mi], bh[ni], acc[mi][ni], 0, 0, 0);
      }
  }
  #pragma unroll
  for (int mi = 0; mi < 2; mi++)
    #pragma unroll
    for (int ni = 0; ni < 2; ni++)
      #pragma unroll
      for (int r = 0; r < 4; r++) {
        int row = r0 + mi * 16 + quad * 4 + r;   // C/D: col=lane&15, row=quad*4+reg (m89)
        int col = c0 + ni * 16 + lr;
        float o = acc[mi][ni][r];
        if (bias)  o += bias[col];
        if (resid) o += resid[(size_t)row * DMODEL + col];
        C[(size_t)row * DMODEL + col] = o;
      }
}

__global__ __launch_bounds__(256) void proj_mfma(
    const unsigned short* __restrict__ qnh, const unsigned short* __restrict__ qnl,
    const unsigned short* __restrict__ kh, const unsigned short* __restrict__ kl,
    const unsigned short* __restrict__ vh, const unsigned short* __restrict__ vl,
    const unsigned short* __restrict__ Wqh, const unsigned short* __restrict__ Wql,
    const unsigned short* __restrict__ Wkh, const unsigned short* __restrict__ Wkl,
    const unsigned short* __restrict__ Wvh, const unsigned short* __restrict__ Wvl,
    float* __restrict__ Qp, float* __restrict__ Kp, float* __restrict__ Vp) {
  const unsigned short *Ah, *Al, *Wh, *Wl; float* C;
  if (blockIdx.z == 0)      { Ah = qnh; Al = qnl; Wh = Wqh; Wl = Wql; C = Qp; }
  else if (blockIdx.z == 1) { Ah = kh;  Al = kl;  Wh = Wkh; Wl = Wkl; C = Kp; }
  else                      { Ah = vh;  Al = vl;  Wh = Wvh; Wl = Wvl; C = Vp; }
  mfma_gemm_body(Ah, Al, Wh, Wl, C, nullptr, nullptr);
}

__global__ __launch_bounds__(256) void fc_mfma(
    const unsigned short* __restrict__ AOh, const unsigned short* __restrict__ AOl,
    const unsigned short* __restrict__ Wfh, const unsigned short* __restrict__ Wfl,
    const float* __restrict__ bfc, const float* __restrict__ resid,
    float* __restrict__ out) {
  mfma_gemm_body(AOh, AOl, Wfh, Wfl, out, bfc, resid);
}

// ---------------- attention per (b, dk): K in regs, V in LDS, vectorized sim/attn ----------------
// grid (8 qtiles x 64 dk x 4 b); block 256 = 4 waves; wave handles 16 q rows.
__global__ __launch_bounds__(256, 3) void attn2_kernel(
    const float* __restrict__ Qp, const float* __restrict__ Kp, const float* __restrict__ Vp,
    const float* __restrict__ sim, float* __restrict__ attn_out,
    unsigned short* __restrict__ AOh, unsigned short* __restrict__ AOl) {
  __shared__ float Vt[8][516];   // padded: conflict-free staging writes, aligned b128 reads
  __shared__ float Qs[64][8];
  const int qt = blockIdx.x, dk = blockIdx.y, b = blockIdx.z;
  const int t = threadIdx.x;
  const float* Vbase = Vp + (size_t)b * LSEQ * DMODEL + dk * 8;
  #pragma unroll
  for (int it = 0; it < 16; it++) {
    int idx = it * 256 + t;
    int l = idx >> 3, j = idx & 7;
    Vt[j][l] = Vbase[(size_t)l * DMODEL + j];
  }
  const float* Qbase = Qp + ((size_t)b * LSEQ + qt * 64) * DMODEL + dk * 8;
  #pragma unroll
  for (int it = 0; it < 2; it++) {
    int idx = it * 256 + t;
    int l = idx >> 3, j = idx & 7;
    Qs[l][j] = Qbase[(size_t)l * DMODEL + j];
  }
  const int lane = t & 63, w = t >> 6;
  const float* Kbase = Kp + (size_t)b * LSEQ * DMODEL + dk * 8;
  float Kr[2][8][4];                         // [chunk][feature][sub]: kp = c*256 + lane*4 + s
  #pragma unroll
  for (int c = 0; c < 2; c++)
    #pragma unroll
    for (int s = 0; s < 4; s++) {
      const float* kr = Kbase + (size_t)(c * 256 + lane * 4 + s) * DMODEL;
      float4 a  = *(const float4*)kr;
      float4 bb = *(const float4*)(kr + 4);
      Kr[c][0][s] = a.x;  Kr[c][1][s] = a.y;  Kr[c][2][s] = a.z;  Kr[c][3][s] = a.w;
      Kr[c][4][s] = bb.x; Kr[c][5][s] = bb.y; Kr[c][6][s] = bb.z; Kr[c][7][s] = bb.w;
    }
  __syncthreads();

  for (int qi = 0; qi < 16; qi++) {
    const int ql = w * 16 + qi;
    const int q  = qt * 64 + ql;
    const size_t rowoff = (((size_t)(b * 64 + dk) * LSEQ) + q) * LSEQ;
    float4 sv0 = *(const float4*)(sim + rowoff + lane * 4);
    float4 sv1 = *(const float4*)(sim + rowoff + 256 + lane * 4);
    float svf[2][4] = {{sv0.x, sv0.y, sv0.z, sv0.w}, {sv1.x, sv1.y, sv1.z, sv1.w}};
    float qreg[8];
    #pragma unroll
    for (int j = 0; j < 8; j++) qreg[j] = Qs[ql][j];   // LDS broadcast
    float sc[2][4];
    #pragma unroll
    for (int c = 0; c < 2; c++)
      #pragma unroll
      for (int s = 0; s < 4; s++) {
        float d = 0.0f;
        #pragma unroll
        for (int j = 0; j < 8; j++) d = fmaf(qreg[j], Kr[c][j][s], d);
        sc[c][s] = fmaf(d, 0.125f, svf[c][s]);
      }
    float m = sc[0][0];
    #pragma unroll
    for (int c = 0; c < 2; c++)
      #pragma unroll
      for (int s = 0; s < 4; s++) m = fmaxf(m, sc[c][s]);
    #pragma unroll
    for (int o = 1; o < 64; o <<= 1) m = fmaxf(m, __shfl_xor(m, o));
    float p[2][4]; float sum = 0.0f;
    #pragma unroll
    for (int c = 0; c < 2; c++)
      #pragma unroll
      for (int s = 0; s < 4; s++) { p[c][s] = __expf(sc[c][s] - m); sum += p[c][s]; }
    #pragma unroll
    for (int o = 1; o < 64; o <<= 1) sum += __shfl_xor(sum, o);
    const float r = 1.0f / sum;
    #pragma unroll
    for (int c = 0; c < 2; c++)
      #pragma unroll
      for (int s = 0; s < 4; s++) p[c][s] *= r;
    float4 st0 = {p[0][0], p[0][1], p[0][2], p[0][3]};
    float4 st1 = {p[1][0], p[1][1], p[1][2], p[1][3]};
    *(float4*)(attn_out + rowoff + lane * 4) = st0;
    *(float4*)(attn_out + rowoff + 256 + lane * 4) = st1;
    // PV
    float pv[8];
    #pragma unroll
    for (int j = 0; j < 8; j++) {
      float acc = 0.0f;
      #pragma unroll
      for (int c = 0; c < 2; c++) {
        float4 vv = *(const float4*)&Vt[j][c * 256 + lane * 4];
        acc = fmaf(p[c][0], vv.x, acc);
        acc = fmaf(p[c][1], vv.y, acc);
        acc = fmaf(p[c][2], vv.z, acc);
        acc = fmaf(p[c][3], vv.w, acc);
      }
      pv[j] = acc;
    }
    #pragma unroll
    for (int j = 0; j < 8; j++)
      #pragma unroll
      for (int o = 1; o < 64; o <<= 1) pv[j] += __shfl_xor(pv[j], o);
    if (lane < 2) {
      us8 ov;
      #pragma unroll
      for (int j = 0; j < 8; j++) {
        unsigned short h, l;
        split2(pv[j], h, l);
        ov[j] = (lane == 0) ? h : l;
      }
      unsigned short* dst = ((lane == 0) ? AOh : AOl) + ((size_t)b * LSEQ + q) * DMODEL + dk * 8;
      *(us8*)dst = ov;
    }
  }
}

extern "C" void kernel_launch(void* const* d_in, const int* in_sizes, int n_in,
                              void* d_out, int out_size, void* d_ws, size_t ws_size,
                              hipStream_t stream) {
  const float* q    = (const float*)d_in[0];
  const float* k    = (const float*)d_in[1];
  const float* v    = (const float*)d_in[2];
  const float* sim  = (const float*)d_in[3];
  const float* Wq   = (const float*)d_in[4];
  const float* Wk   = (const float*)d_in[5];
  const float* Wv   = (const float*)d_in[6];
  const float* Wfc  = (const float*)d_in[7];
  const float* bfc  = (const float*)d_in[8];
  const float* ln_g = (const float*)d_in[9];
  const float* ln_b = (const float*)d_in[10];

  float* out  = (float*)d_out;                          // [B,L,DM] (also holds Qp until fc)
  float* attn = out + (size_t)NTOK * DMODEL;            // [B,64,L,L]

  // scratch inside attn region (dead before attn2 writes it): k/v bf16 hi/lo
  unsigned short* kh = (unsigned short*)attn;
  unsigned short* kl = kh + (size_t)NTOK * DMODEL;
  unsigned short* vh = kl + (size_t)NTOK * DMODEL;
  unsigned short* vl = vh + (size_t)NTOK * DMODEL;
  float* Qp = out;                                      // out region reused; fc overwrites at end

  // ws layout: qn hi/lo (reused as AO hi/lo), W hi/lo x4, Kp, Vp  = 16 MB
  unsigned short* qnh = (unsigned short*)d_ws;
  unsigned short* qnl = qnh + (size_t)NTOK * DMODEL;
  unsigned short* Wqh = qnl + (size_t)NTOK * DMODEL;
  unsigned short* Wql = Wqh + DMODEL * DMODEL;
  unsigned short* Wkh = Wql + DMODEL * DMODEL;
  unsigned short* Wkl = Wkh + DMODEL * DMODEL;
  unsigned short* Wvh = Wkl + DMODEL * DMODEL;
  unsigned short* Wvl = Wvh + DMODEL * DMODEL;
  unsigned short* Wfh = Wvl + DMODEL * DMODEL;
  unsigned short* Wfl = Wfh + DMODEL * DMODEL;
  float* Kp = (float*)(Wfl + DMODEL * DMODEL);
  float* Vp = Kp + (size_t)NTOK * DMODEL;
  unsigned short* AOh = qnh;   // qn dead after proj
  unsigned short* AOl = qnl;

  ln_kernel<<<dim3(NTOK), dim3(256), 0, stream>>>(q, ln_g, ln_b, qnh, qnl);
  conv_kernel<<<dim3(1024, 6), dim3(256), 0, stream>>>(k, v, Wq, Wk, Wv, Wfc,
      kh, kl, vh, vl, Wqh, Wql, Wkh, Wkl, Wvh, Wvl, Wfh, Wfl);
  proj_mfma<<<dim3(8, 32, 3), dim3(256), 0, stream>>>(qnh, qnl, kh, kl, vh, vl,
      Wqh, Wql, Wkh, Wkl, Wvh, Wvl, Qp, Kp, Vp);
  attn2_kernel<<<dim3(8, 64, 4), dim3(256), 0, stream>>>(Qp, Kp, Vp, sim, attn, AOh, AOl);
  fc_mfma<<<dim3(8, 32, 1), dim3(256), 0, stream>>>(AOh, AOl, Wfh, Wfl, bfc, q, out);
}